// Round 18
// baseline (75.866 us; speedup 1.0000x reference)
//
#include <hip/hip_runtime.h>
#include <stdint.h>

#define B_IMG  8
#define NANCH  17328          // A*HW = 3*5776
#define NCLS   80
#define TOPK   200
#define NTHR   256
#define NTHRB  512            // backend block size (8 waves)
#define CHUNK  64             // anchors per scatter block
#define NCHK   ((NANCH + CHUNK - 1) / CHUNK)   // 271
#define NCHKP  272            // padded
#define SLOT   12             // per-(bc,chunk) slots; Poisson(1.28) P(>=12)~1e-8
#define NPOS   (NCHK * SLOT)  // 3252 candidate positions per (b,c)
#define NBC    (B_IMG * NCLS) // 640
#define THRESH_HI 0.98f       // E[count]=347, need>=200 (7.9 sigma margin)

// ---------------------------------------------------------------------------
// helpers (proven rounds 1-17)
// ---------------------------------------------------------------------------
__device__ __forceinline__ void hist_add(float s, unsigned int* hist) {
  if (s > 0.5f) {
    unsigned int bin = (__float_as_uint(s) - 0x3F000000u) >> 15;
    if (bin > 255u) bin = 255u;
    atomicAdd(&hist[bin], 1u);
  }
}

// ---------------------------------------------------------------------------
// K1 (scatter, rd8/rd12-proven): atomic-free deterministic-slot scatter
// ---------------------------------------------------------------------------
__global__ __launch_bounds__(NTHR) void scatter_k(
    const float* __restrict__ scores,
    unsigned char* __restrict__ cnt2,         // [NBC][NCHKP]
    unsigned long long* __restrict__ cand) {  // [NBC][NCHK][SLOT]
  const int nb = blockIdx.x;
  const int b  = blockIdx.y;
  const int tid = threadIdx.x;
  const int wv = tid >> 6, lane = tid & 63;
  const int n0 = nb * CHUNK;

  __shared__ float tile[CHUNK][81];           // pad 81: conflict-free col reads

  const int nrow = (NANCH - n0 < CHUNK) ? (NANCH - n0) : CHUNK;
  const int nf4 = nrow * (NCLS / 4);
  const float4* src4 = (const float4*)(scores + (size_t)(b * NANCH + n0) * NCLS);
  for (int f = tid; f < nf4; f += NTHR) {
    float4 v = src4[f];                       // fully coalesced
    int n = f / 20, c4 = (f - n * 20) * 4;
    tile[n][c4] = v.x; tile[n][c4 + 1] = v.y;
    tile[n][c4 + 2] = v.z; tile[n][c4 + 3] = v.w;
  }
  __syncthreads();

  const bool rv = (lane < nrow);
  const unsigned long long lt = (1ull << lane) - 1ull;
  const int cbase = wv * 20;
#pragma unroll 4
  for (int cc = 0; cc < 20; ++cc) {
    const int c = cbase + cc;
    const int bc = b * NCLS + c;
    float s = rv ? tile[lane][c] : 0.f;
    const bool cd = (s > THRESH_HI);
    unsigned long long bal = __ballot(cd);
    if (cd) {
      unsigned int r = (unsigned int)__popcll(bal & lt);
      if (r < SLOT)                           // dropped -> cnt poisons via >SLOT
        cand[((size_t)bc * NCHK + nb) * SLOT + r] =
            ((unsigned long long)__float_as_uint(s) << 32) |
            (unsigned long long)(0xFFFFFFFFu - (unsigned int)(n0 + lane));
    }
    if (lane == 0)
      cnt2[(size_t)bc * NCHKP + nb] = (unsigned char)__popcll(bal);
  }
}

// ---------------------------------------------------------------------------
// K2 (backend): compact -> bitonic sort -> gather -> SPARSE ballot-free
// supbuild (flat pair loop, LDS atomicOr of rare suppress bits) ->
// wave-0 bit-scan -> emit. Fallback: proven strided scan.
// ---------------------------------------------------------------------------
__global__ __launch_bounds__(NTHRB) void backend_k(
    const float* __restrict__ scores, const float* __restrict__ boxes,
    const unsigned char* __restrict__ cnt2, const unsigned long long* __restrict__ cand,
    float* __restrict__ out) {
  const int bc = blockIdx.x;
  const int b = bc / NCLS;
  const int c = bc - b * NCLS;
  const int tid = threadIdx.x;
  const int lane = tid & 63;
  const unsigned long long lt = (1ull << lane) - 1ull;

  __shared__ unsigned long long selk[512];                    // 4 KB, in-place
  __shared__ unsigned int hist[256];                          // fallback only
  __shared__ __align__(16) float4 sbox[256];                  // 4 KB
  __shared__ float sar[256], ssc[256];
  __shared__ int skeep[256];
  __shared__ __align__(16) unsigned long long sup[TOPK][4];   // 6.4 KB
  __shared__ __align__(16) float eout[TOPK * 6];              // 4.8 KB
  __shared__ unsigned int sh_cutbits;
  __shared__ int sh_sel, sh_bad;

  if (tid == 0) { sh_sel = 0; sh_bad = 0; }
  __syncthreads();

  // ---- phase 1: optimistic ballot-compact of ALL candidates (~347) ---------
  const unsigned long long* cb0 = cand + (size_t)bc * NCHK * SLOT;
  const unsigned char* ct0 = cnt2 + (size_t)bc * NCHKP;
  for (int p = tid; p < NPOS; p += NTHRB) {
    const int ch = p / SLOT;
    const int sl = p - ch * SLOT;
    unsigned int ci = (unsigned int)ct0[ch];
    if (sl == 0 && ci > SLOT) sh_bad = 1;     // overflowed chunk
    unsigned long long k = 0ull;
    bool pred = (sl < (int)ci);
    if (pred) k = cb0[p];
    unsigned long long bal = __ballot(pred);
    if (bal) {
      int base0 = 0;
      if (lane == 0) base0 = atomicAdd(&sh_sel, (int)__popcll(bal));
      base0 = __shfl(base0, 0, 64);
      if (pred) {
        int pos = base0 + (int)__popcll(bal & lt);
        if (pos < 512) selk[pos] = k;         // M>512 -> fb (count still exact)
      }
    }
  }
  __syncthreads();

  int Msel = sh_sel;
  const bool fb = (sh_bad != 0) || (Msel < TOPK) || (Msel > 512);  // uniform

  if (fb) {
    // ---- fallback: proven strided 2-pass full scan (rd1 code) --------------
    if (tid < 256) hist[tid] = 0u;
    if (tid == 0) sh_sel = 0;
    __syncthreads();
    const float* src = scores + (size_t)b * NANCH * NCLS + c;
    for (int i = tid; i < NANCH; i += NTHRB) hist_add(src[(size_t)i * NCLS], hist);
    __syncthreads();
    if (tid == 0) {
      unsigned int acc = 0;
      int cut = 0;
      for (int bin = 255; bin >= 0; --bin) {
        acc += hist[bin];
        if (acc >= TOPK) { cut = bin; break; }
      }
      sh_cutbits = 0x3F000000u + ((unsigned int)cut << 15);
    }
    __syncthreads();
    const unsigned int cutbits = sh_cutbits;
    for (int i = tid; i < NANCH; i += NTHRB) {
      float s = src[(size_t)i * NCLS];
      if (s > 0.5f && __float_as_uint(s) >= cutbits) {
        int slot = atomicAdd(&sh_sel, 1);
        if (slot < 512)
          selk[slot] = ((unsigned long long)__float_as_uint(s) << 32) |
                       (unsigned long long)(0xFFFFFFFFu - (unsigned int)i);
      }
    }
    __syncthreads();
    Msel = sh_sel; if (Msel > 512) Msel = 512;
  }

  // ---- phase 2: zero-pad + bitonic sort, descending (rd8/rd14-proven) ------
  const int S = (Msel <= 256) ? 256 : 512;
  for (int j = Msel + tid; j < S; j += NTHRB) selk[j] = 0ull;

  for (int size = 2; size <= S; size <<= 1) {
    for (int st = size >> 1; st > 0; st >>= 1) {
      __syncthreads();
      for (int t = tid; t < (S >> 1); t += NTHRB) {
        int lo = 2 * t - (t & (st - 1));
        int hi = lo + st;
        bool desc = ((lo & size) == 0);
        unsigned long long a = selk[lo], bb = selk[hi];
        if ((a < bb) == desc) { selk[lo] = bb; selk[hi] = a; }
      }
    }
  }
  __syncthreads();

  // ---- phase 3: gather top-200 boxes (tid<256) + zero sup (tid>=256) -------
  if (tid < 256) {
    unsigned long long key = selk[tid];
    int valid = (tid < TOPK) && (key != 0ull);
    unsigned int idx = 0xFFFFFFFFu - (unsigned int)(key & 0xFFFFFFFFull);
    float4 bx = make_float4(0.f, 0.f, 0.f, 0.f);
    if (valid) bx = ((const float4*)boxes)[(size_t)b * NANCH + idx];
    sbox[tid] = bx;
    sar[tid] = __fmul_rn(bx.z - bx.x, bx.w - bx.y);   // _rn: block FMA contraction
    ssc[tid] = valid ? __uint_as_float((unsigned int)(key >> 32)) : 0.f;
    skeep[tid] = valid;
  } else {
    unsigned long long* sw = (unsigned long long*)&sup[0][0];
    for (int f = tid - 256; f < TOPK * 4; f += 256) sw[f] = 0ull;
  }
  __syncthreads();

  // ---- phase 4: SPARSE supbuild — flat pair loop, no ballots ---------------
  // 1600 tasks = (i, 25-wide j-block); per pair the rd12-proven decision
  // (rcp + guard band + exact fdiv re-decide). Suppressing pairs (~1%) set
  // their bit via LDS atomicOr. Zero/NaN boxes never suppress (inter=0/NaN).
  {
    unsigned long long* sw = (unsigned long long*)&sup[0][0];
    for (int t2 = tid; t2 < 1600; t2 += NTHRB) {
      const int i = t2 >> 3;
      const int j0 = (t2 & 7) * 25;
      if (j0 + 24 <= i) continue;             // task entirely below diagonal
      const float4 bi = sbox[i];
      const float ai = sar[i];
#pragma unroll 5
      for (int q = 0; q < 25; ++q) {
        const int j = j0 + q;
        if (j <= i) continue;
        const float4 bj = sbox[j];
        float xx1 = fmaxf(bi.x, bj.x);
        float yy1 = fmaxf(bi.y, bj.y);
        float xx2 = fminf(bi.z, bj.z);
        float yy2 = fminf(bi.w, bj.w);
        float iw = fmaxf(0.f, __fsub_rn(xx2, xx1));
        float ih = fmaxf(0.f, __fsub_rn(yy2, yy1));
        float inter = __fmul_rn(iw, ih);
        float denom = __fsub_rn(__fadd_rn(ai, sar[j]), inter);
        float qq = __fmul_rn(inter, __builtin_amdgcn_rcpf(denom));
        bool s = qq > 0.5f;
        if (fabsf(qq - 0.5f) < 1e-5f)         // ~never: exact IEEE re-decision
          s = __fdiv_rn(inter, denom) > 0.5f;
        if (s)                                // rare (~1%): sparse bit set
          atomicOr(&sw[i * 4 + (j >> 6)], 1ull << (j & 63));
      }
    }
  }
  __syncthreads();

  // ---- phase 5: serial bit-scan, wave 0 (rd12-proven) ----------------------
  if (tid < 64) {
    unsigned long long k0 = __ballot(skeep[tid] != 0);
    unsigned long long k1 = __ballot(skeep[64 + tid] != 0);
    unsigned long long k2 = __ballot(skeep[128 + tid] != 0);
    unsigned long long k3 = __ballot(skeep[192 + tid] != 0);  // 200..255 are 0
#define NMS_SCAN_WORD(KW, BASE, CNT)                                     \
    _Pragma("unroll 8")                                                  \
    for (int li = 0; li < (CNT); ++li) {                                 \
      const ulonglong2* s2p =                                            \
          reinterpret_cast<const ulonglong2*>(&sup[(BASE) + li][0]);     \
      ulonglong2 sa = s2p[0];                                            \
      ulonglong2 sb = s2p[1];                                            \
      unsigned long long m = 0ull - ((KW >> li) & 1ull);                 \
      k0 &= ~(sa.x & m); k1 &= ~(sa.y & m);                              \
      k2 &= ~(sb.x & m); k3 &= ~(sb.y & m);                              \
    }
    NMS_SCAN_WORD(k0, 0, 64)
    NMS_SCAN_WORD(k1, 64, 64)
    NMS_SCAN_WORD(k2, 128, 64)
    NMS_SCAN_WORD(k3, 192, 8)
#undef NMS_SCAN_WORD
    skeep[tid]        = (int)((k0 >> tid) & 1ull);
    skeep[64 + tid]   = (int)((k1 >> tid) & 1ull);
    skeep[128 + tid]  = (int)((k2 >> tid) & 1ull);
    skeep[192 + tid]  = (int)((k3 >> tid) & 1ull);
  }
  __syncthreads();

  // ---- phase 6: emit via LDS stage + coalesced float4 stores (proven) ------
  if (tid < TOPK) {
    int kp = skeep[tid];
    float4 bx = sbox[tid];
    eout[tid * 6 + 0] = kp ? bx.x : 0.f;
    eout[tid * 6 + 1] = kp ? bx.y : 0.f;
    eout[tid * 6 + 2] = kp ? bx.z : 0.f;
    eout[tid * 6 + 3] = kp ? bx.w : 0.f;
    eout[tid * 6 + 4] = kp ? ssc[tid] : 0.f;
    eout[tid * 6 + 5] = kp ? (float)c : 0.f;
  }
  __syncthreads();

  float4* out4 = (float4*)(out + (size_t)bc * (TOPK * 6));
  const float4* e4 = (const float4*)eout;
  for (int f = tid; f < (TOPK * 6) / 4; f += NTHRB) out4[f] = e4[f];
}

// ---------------------------------------------------------------------------
// Fallback: proven monolithic kernel (strided reads), used only if ws tiny
// ---------------------------------------------------------------------------
__global__ __launch_bounds__(NTHR) void select_nms_k(
    const float* __restrict__ boxes, const float* __restrict__ scores,
    float* __restrict__ out) {
  const int blk = blockIdx.x;
  const int b = blk / NCLS;
  const int c = blk - b * NCLS;
  const int tid = threadIdx.x;

  __shared__ unsigned int hist[256];
  __shared__ unsigned long long keys[1024];
  __shared__ float sx1[TOPK], sy1[TOPK], sx2[TOPK], sy2[TOPK], sar[TOPK], ssc[TOPK];
  __shared__ int skeep[TOPK];
  __shared__ unsigned int sh_cutbits;
  __shared__ int sh_m;

  const float* src = scores + (size_t)b * NANCH * NCLS + c;

  for (int j = tid; j < 256; j += NTHR) hist[j] = 0;
  if (tid == 0) sh_m = 0;
  __syncthreads();

  for (int i = tid; i < NANCH; i += NTHR) hist_add(src[(size_t)i * NCLS], hist);
  __syncthreads();

  if (tid == 0) {
    unsigned int acc = 0;
    int cut = 0;
    for (int bin = 255; bin >= 0; --bin) {
      acc += hist[bin];
      if (acc >= TOPK) { cut = bin; break; }
    }
    sh_cutbits = 0x3F000000u + ((unsigned int)cut << 15);
  }
  __syncthreads();
  const unsigned int cutbits = sh_cutbits;

  for (int i = tid; i < NANCH; i += NTHR) {
    float s = src[(size_t)i * NCLS];
    if (s > 0.5f && __float_as_uint(s) >= cutbits) {
      int slot = atomicAdd(&sh_m, 1);
      if (slot < 1024)
        keys[slot] = ((unsigned long long)__float_as_uint(s) << 32) |
                     (unsigned long long)(0xFFFFFFFFu - (unsigned int)i);
    }
  }
  __syncthreads();
  int M = sh_m; if (M > 1024) M = 1024;
  for (int j = M + tid; j < 1024; j += NTHR) keys[j] = 0ull;

  for (int size = 2; size <= 1024; size <<= 1) {
    for (int st = size >> 1; st > 0; st >>= 1) {
      __syncthreads();
      for (int t = tid; t < 512; t += NTHR) {
        int lo = 2 * t - (t & (st - 1));
        int hi = lo + st;
        bool desc = ((lo & size) == 0);
        unsigned long long a = keys[lo], bb = keys[hi];
        if ((a < bb) == desc) { keys[lo] = bb; keys[hi] = a; }
      }
    }
  }
  __syncthreads();

  if (tid < TOPK) {
    unsigned long long key = keys[tid];
    int valid = (key != 0ull);
    float sc = __uint_as_float((unsigned int)(key >> 32));
    unsigned int idx = 0xFFFFFFFFu - (unsigned int)(key & 0xFFFFFFFFull);
    float4 bx = make_float4(0.f, 0.f, 0.f, 0.f);
    if (valid) bx = ((const float4*)boxes)[(size_t)b * NANCH + idx];
    sx1[tid] = bx.x; sy1[tid] = bx.y; sx2[tid] = bx.z; sy2[tid] = bx.w;
    sar[tid] = __fmul_rn(bx.z - bx.x, bx.w - bx.y);
    ssc[tid] = valid ? sc : 0.f;
    skeep[tid] = valid;
  }
  __syncthreads();

  if (tid < 64) {
    const int lane = tid;
    float x1v[4], y1v[4], x2v[4], y2v[4], av[4];
    int km = 0;
#pragma unroll
    for (int r = 0; r < 4; ++r) {
      int j = lane + (r << 6);
      if (j < TOPK) {
        x1v[r] = sx1[j]; y1v[r] = sy1[j]; x2v[r] = sx2[j]; y2v[r] = sy2[j];
        av[r] = sar[j];
        if (skeep[j]) km |= (1 << r);
      } else {
        x1v[r] = 0.f; y1v[r] = 0.f; x2v[r] = 0.f; y2v[r] = 0.f; av[r] = 0.f;
      }
    }
#pragma unroll
    for (int ri = 0; ri < 4; ++ri) {
      const int imax = (ri == 3) ? (TOPK - 192) : 64;
      for (int li = 0; li < imax; ++li) {
        const int i = (ri << 6) + li;
        int kmi = __shfl(km, li, 64);
        if (!((kmi >> ri) & 1)) continue;
        float xi1 = __shfl(x1v[ri], li, 64);
        float yi1 = __shfl(y1v[ri], li, 64);
        float xi2 = __shfl(x2v[ri], li, 64);
        float yi2 = __shfl(y2v[ri], li, 64);
        float ai  = __shfl(av[ri],  li, 64);
#pragma unroll
        for (int r = 0; r < 4; ++r) {
          int j = lane + (r << 6);
          if (j > i && j < TOPK && ((km >> r) & 1)) {
            float xx1 = fmaxf(xi1, x1v[r]);
            float yy1 = fmaxf(yi1, y1v[r]);
            float xx2 = fminf(xi2, x2v[r]);
            float yy2 = fminf(yi2, y2v[r]);
            float iw = fmaxf(0.f, __fsub_rn(xx2, xx1));
            float ih = fmaxf(0.f, __fsub_rn(yy2, yy1));
            float inter = __fmul_rn(iw, ih);
            float denom = __fsub_rn(__fadd_rn(ai, av[r]), inter);
            float iou = __fdiv_rn(inter, denom);
            if (iou > 0.5f) km &= ~(1 << r);
          }
        }
      }
    }
#pragma unroll
    for (int r = 0; r < 4; ++r) {
      int j = lane + (r << 6);
      if (j < TOPK) skeep[j] = (km >> r) & 1;
    }
  }
  __syncthreads();

  const size_t base = ((size_t)b * NCLS + c) * (TOPK * 6);
  for (int f = tid; f < TOPK * 6; f += NTHR) {
    int k = f / 6, comp = f - k * 6;
    float v = 0.f;
    if (skeep[k]) {
      switch (comp) {
        case 0: v = sx1[k]; break;
        case 1: v = sy1[k]; break;
        case 2: v = sx2[k]; break;
        case 3: v = sy2[k]; break;
        case 4: v = ssc[k]; break;
        default: v = (float)c; break;
      }
    }
    out[base + f] = v;
  }
}

// ---------------------------------------------------------------------------
extern "C" void kernel_launch(void* const* d_in, const int* in_sizes, int n_in,
                              void* d_out, int out_size, void* d_ws, size_t ws_size,
                              hipStream_t stream) {
  (void)in_sizes; (void)n_in; (void)out_size;
  const float* boxes  = (const float*)d_in[0];
  const float* scores = (const float*)d_in[1];
  float* out = (float*)d_out;

  const size_t need_c2 = (size_t)NBC * NCHKP;                          // 174 KB
  const size_t need_cd = (size_t)NBC * NCHK * SLOT * sizeof(uint64_t); // 16.6 MB
  const size_t need = need_c2 + need_cd;

  if (ws_size >= need) {
    char* w = (char*)d_ws;
    unsigned char* cnt2      = (unsigned char*)w;       w += need_c2;
    unsigned long long* cand = (unsigned long long*)w;

    scatter_k<<<dim3(NCHK, B_IMG), NTHR, 0, stream>>>(scores, cnt2, cand);
    backend_k<<<NBC, NTHRB, 0, stream>>>(scores, boxes, cnt2, cand, out);
  } else {
    select_nms_k<<<NBC, NTHR, 0, stream>>>(boxes, scores, out);
  }
}

// Round 19
// 72.772 us; speedup vs baseline: 1.0425x; 1.0425x over previous
//
#include <hip/hip_runtime.h>
#include <stdint.h>

#define B_IMG  8
#define NANCH  17328          // A*HW = 3*5776
#define NCLS   80
#define TOPK   200
#define NTHR   256
#define NTHRB  512            // backend block size (8 waves)
#define CHUNK  64             // anchors per scatter block
#define NCHK   ((NANCH + CHUNK - 1) / CHUNK)   // 271
#define NCHKP  272            // padded
#define SLOT   12             // per-(bc,chunk) slots; Poisson(1.28) P(>=12)~1e-8
#define NPOS   (NCHK * SLOT)  // 3252 candidate positions per (b,c)
#define NBC    (B_IMG * NCLS) // 640
#define THRESH_HI 0.98f       // E[count]=347, need>=200 (7.9 sigma margin)

// ---------------------------------------------------------------------------
// helpers (proven rounds 1-18)
// ---------------------------------------------------------------------------
__device__ __forceinline__ void hist_add(float s, unsigned int* hist) {
  if (s > 0.5f) {
    unsigned int bin = (__float_as_uint(s) - 0x3F000000u) >> 15;
    if (bin > 255u) bin = 255u;
    atomicAdd(&hist[bin], 1u);
  }
}

// ---------------------------------------------------------------------------
// K1 (scatter, rd8/rd12-proven): atomic-free deterministic-slot scatter
// ---------------------------------------------------------------------------
__global__ __launch_bounds__(NTHR) void scatter_k(
    const float* __restrict__ scores,
    unsigned char* __restrict__ cnt2,         // [NBC][NCHKP]
    unsigned long long* __restrict__ cand) {  // [NBC][NCHK][SLOT]
  const int nb = blockIdx.x;
  const int b  = blockIdx.y;
  const int tid = threadIdx.x;
  const int wv = tid >> 6, lane = tid & 63;
  const int n0 = nb * CHUNK;

  __shared__ float tile[CHUNK][81];           // pad 81: conflict-free col reads

  const int nrow = (NANCH - n0 < CHUNK) ? (NANCH - n0) : CHUNK;
  const int nf4 = nrow * (NCLS / 4);
  const float4* src4 = (const float4*)(scores + (size_t)(b * NANCH + n0) * NCLS);
  for (int f = tid; f < nf4; f += NTHR) {
    float4 v = src4[f];                       // fully coalesced
    int n = f / 20, c4 = (f - n * 20) * 4;
    tile[n][c4] = v.x; tile[n][c4 + 1] = v.y;
    tile[n][c4 + 2] = v.z; tile[n][c4 + 3] = v.w;
  }
  __syncthreads();

  const bool rv = (lane < nrow);
  const unsigned long long lt = (1ull << lane) - 1ull;
  const int cbase = wv * 20;
#pragma unroll 4
  for (int cc = 0; cc < 20; ++cc) {
    const int c = cbase + cc;
    const int bc = b * NCLS + c;
    float s = rv ? tile[lane][c] : 0.f;
    const bool cd = (s > THRESH_HI);
    unsigned long long bal = __ballot(cd);
    if (cd) {
      unsigned int r = (unsigned int)__popcll(bal & lt);
      if (r < SLOT)                           // dropped -> cnt poisons via >SLOT
        cand[((size_t)bc * NCHK + nb) * SLOT + r] =
            ((unsigned long long)__float_as_uint(s) << 32) |
            (unsigned long long)(0xFFFFFFFFu - (unsigned int)(n0 + lane));
    }
    if (lane == 0)
      cnt2[(size_t)bc * NCHKP + nb] = (unsigned char)__popcll(bal);
  }
}

// ---------------------------------------------------------------------------
// K2 (backend, rd17-proven champion): compact -> BITONIC sort -> gather ->
// supbuild (8 waves, dieted wmask + rcp/guard) -> wave-0 bit-scan -> emit.
// Fallback (count<200 | overflow | count>512): proven strided scan.
// ---------------------------------------------------------------------------
__global__ __launch_bounds__(NTHRB) void backend_k(
    const float* __restrict__ scores, const float* __restrict__ boxes,
    const unsigned char* __restrict__ cnt2, const unsigned long long* __restrict__ cand,
    float* __restrict__ out) {
  const int bc = blockIdx.x;
  const int b = bc / NCLS;
  const int c = bc - b * NCLS;
  const int tid = threadIdx.x;
  const int wv = tid >> 6, lane = tid & 63;
  const unsigned long long lt = (1ull << lane) - 1ull;

  __shared__ unsigned long long selk[512];                    // 4 KB, in-place
  __shared__ unsigned int hist[256];                          // fallback only
  __shared__ float sx1[256], sy1[256], sx2[256], sy2[256], sar[256], ssc[256];
  __shared__ int skeep[256];
  __shared__ __align__(16) unsigned long long sup[TOPK][4];   // 6.4 KB
  __shared__ __align__(16) float eout[TOPK * 6];              // 4.8 KB
  __shared__ unsigned int sh_cutbits;
  __shared__ int sh_sel, sh_bad;

  if (tid == 0) { sh_sel = 0; sh_bad = 0; }
  __syncthreads();

  // ---- phase 1: optimistic ballot-compact of ALL candidates (~347) ---------
  const unsigned long long* cb0 = cand + (size_t)bc * NCHK * SLOT;
  const unsigned char* ct0 = cnt2 + (size_t)bc * NCHKP;
  for (int p = tid; p < NPOS; p += NTHRB) {
    const int ch = p / SLOT;
    const int sl = p - ch * SLOT;
    unsigned int ci = (unsigned int)ct0[ch];
    if (sl == 0 && ci > SLOT) sh_bad = 1;     // overflowed chunk
    unsigned long long k = 0ull;
    bool pred = (sl < (int)ci);
    if (pred) k = cb0[p];
    unsigned long long bal = __ballot(pred);
    if (bal) {
      int base0 = 0;
      if (lane == 0) base0 = atomicAdd(&sh_sel, (int)__popcll(bal));
      base0 = __shfl(base0, 0, 64);
      if (pred) {
        int pos = base0 + (int)__popcll(bal & lt);
        if (pos < 512) selk[pos] = k;         // M>512 -> fb (count still exact)
      }
    }
  }
  __syncthreads();

  int Msel = sh_sel;
  const bool fb = (sh_bad != 0) || (Msel < TOPK) || (Msel > 512);  // uniform

  if (fb) {
    // ---- fallback: proven strided 2-pass full scan (rd1 code) --------------
    if (tid < 256) hist[tid] = 0u;
    if (tid == 0) sh_sel = 0;
    __syncthreads();
    const float* src = scores + (size_t)b * NANCH * NCLS + c;
    for (int i = tid; i < NANCH; i += NTHRB) hist_add(src[(size_t)i * NCLS], hist);
    __syncthreads();
    if (tid == 0) {
      unsigned int acc = 0;
      int cut = 0;
      for (int bin = 255; bin >= 0; --bin) {
        acc += hist[bin];
        if (acc >= TOPK) { cut = bin; break; }
      }
      sh_cutbits = 0x3F000000u + ((unsigned int)cut << 15);
    }
    __syncthreads();
    const unsigned int cutbits = sh_cutbits;
    for (int i = tid; i < NANCH; i += NTHRB) {
      float s = src[(size_t)i * NCLS];
      if (s > 0.5f && __float_as_uint(s) >= cutbits) {
        int slot = atomicAdd(&sh_sel, 1);
        if (slot < 512)
          selk[slot] = ((unsigned long long)__float_as_uint(s) << 32) |
                       (unsigned long long)(0xFFFFFFFFu - (unsigned int)i);
      }
    }
    __syncthreads();
    Msel = sh_sel; if (Msel > 512) Msel = 512;
  }

  // ---- phase 2: zero-pad + bitonic sort, descending (rd8/rd14-proven) ------
  const int S = (Msel <= 256) ? 256 : 512;
  for (int j = Msel + tid; j < S; j += NTHRB) selk[j] = 0ull;

  for (int size = 2; size <= S; size <<= 1) {
    for (int st = size >> 1; st > 0; st >>= 1) {
      __syncthreads();
      for (int t = tid; t < (S >> 1); t += NTHRB) {
        int lo = 2 * t - (t & (st - 1));
        int hi = lo + st;
        bool desc = ((lo & size) == 0);
        unsigned long long a = selk[lo], bb = selk[hi];
        if ((a < bb) == desc) { selk[lo] = bb; selk[hi] = a; }
      }
    }
  }
  __syncthreads();

  // ---- phase 3: gather top-200 boxes into LDS (proven) ---------------------
  if (tid < 256) {
    unsigned long long key = selk[tid];
    int valid = (tid < TOPK) && (key != 0ull);
    unsigned int idx = 0xFFFFFFFFu - (unsigned int)(key & 0xFFFFFFFFull);
    float4 bx = make_float4(0.f, 0.f, 0.f, 0.f);
    if (valid) bx = ((const float4*)boxes)[(size_t)b * NANCH + idx];
    sx1[tid] = bx.x; sy1[tid] = bx.y; sx2[tid] = bx.z; sy2[tid] = bx.w;
    sar[tid] = __fmul_rn(bx.z - bx.x, bx.w - bx.y);   // _rn: block FMA contraction
    ssc[tid] = valid ? __uint_as_float((unsigned int)(key >> 32)) : 0.f;
    skeep[tid] = valid;
  }
  __syncthreads();

  // ---- phase 4: supbuild, 8 waves, dieted wmask + rcp/guard (rd12-proven) --
  {
    float jx1[4], jy1[4], jx2[4], jy2[4], ja[4];
#pragma unroll
    for (int r = 0; r < 4; ++r) {
      int j = (r << 6) | lane;
      jx1[r] = sx1[j]; jy1[r] = sy1[j]; jx2[r] = sx2[j]; jy2[r] = sy2[j];
      ja[r] = sar[j];
    }
    float nx1 = sx1[wv], ny1 = sy1[wv], nx2 = sx2[wv], ny2 = sy2[wv], na = sar[wv];
    for (int k = 0; k < 25; ++k) {
      const int i = (k << 3) + wv;             // 0..199, wave-uniform
      const float xi1 = nx1, yi1 = ny1, xi2 = nx2, yi2 = ny2, ai = na;
      const int inx = i + 8;
      if (inx < TOPK) {                        // wave-uniform prefetch
        nx1 = sx1[inx]; ny1 = sy1[inx]; nx2 = sx2[inx]; ny2 = sy2[inx];
        na = sar[inx];
      }
      const int d = i >> 6;
      const int il = i & 63;
      unsigned long long dmask = (il == 63) ? 0ull : ((~0ull) << (il + 1));
      if (d == 3) dmask &= 0xFFull;            // j < TOPK within block 3
      unsigned long long w[4];
#pragma unroll
      for (int r = 0; r < 4; ++r) {
        unsigned long long word = 0ull;
        if ((r << 6) + 63 > i) {               // wave-uniform: block has j > i
          const unsigned long long wmask =
              (r > d) ? ((r == 3) ? 0xFFull : ~0ull) : dmask;
          float xx1 = fmaxf(xi1, jx1[r]);
          float yy1 = fmaxf(yi1, jy1[r]);
          float xx2 = fminf(xi2, jx2[r]);
          float yy2 = fminf(yi2, jy2[r]);
          float iw = fmaxf(0.f, __fsub_rn(xx2, xx1));
          float ih = fmaxf(0.f, __fsub_rn(yy2, yy1));
          float inter = __fmul_rn(iw, ih);
          float denom = __fsub_rn(__fadd_rn(ai, ja[r]), inter);
          float q = __fmul_rn(inter, __builtin_amdgcn_rcpf(denom));
          word = __ballot(q > 0.5f);
          unsigned long long gb = __ballot(fabsf(q - 0.5f) < 1e-5f) & wmask;
          if (gb)                              // ~never: exact IEEE re-decision
            word = __ballot(__fdiv_rn(inter, denom) > 0.5f);
          word &= wmask;
        }
        w[r] = word;
      }
      if (lane == 0) {
        ulonglong2* dst = (ulonglong2*)&sup[i][0];
        ulonglong2 t0; t0.x = w[0]; t0.y = w[1];
        ulonglong2 t1; t1.x = w[2]; t1.y = w[3];
        dst[0] = t0; dst[1] = t1;
      }
    }
  }
  __syncthreads();

  // ---- phase 5: serial bit-scan, wave 0 (rd12-proven) ----------------------
  if (tid < 64) {
    unsigned long long k0 = __ballot(skeep[tid] != 0);
    unsigned long long k1 = __ballot(skeep[64 + tid] != 0);
    unsigned long long k2 = __ballot(skeep[128 + tid] != 0);
    unsigned long long k3 = __ballot(skeep[192 + tid] != 0);  // 200..255 are 0
#define NMS_SCAN_WORD(KW, BASE, CNT)                                     \
    _Pragma("unroll 8")                                                  \
    for (int li = 0; li < (CNT); ++li) {                                 \
      const ulonglong2* s2p =                                            \
          reinterpret_cast<const ulonglong2*>(&sup[(BASE) + li][0]);     \
      ulonglong2 sa = s2p[0];                                            \
      ulonglong2 sb = s2p[1];                                            \
      unsigned long long m = 0ull - ((KW >> li) & 1ull);                 \
      k0 &= ~(sa.x & m); k1 &= ~(sa.y & m);                              \
      k2 &= ~(sb.x & m); k3 &= ~(sb.y & m);                              \
    }
    NMS_SCAN_WORD(k0, 0, 64)
    NMS_SCAN_WORD(k1, 64, 64)
    NMS_SCAN_WORD(k2, 128, 64)
    NMS_SCAN_WORD(k3, 192, 8)
#undef NMS_SCAN_WORD
    skeep[tid]        = (int)((k0 >> tid) & 1ull);
    skeep[64 + tid]   = (int)((k1 >> tid) & 1ull);
    skeep[128 + tid]  = (int)((k2 >> tid) & 1ull);
    skeep[192 + tid]  = (int)((k3 >> tid) & 1ull);
  }
  __syncthreads();

  // ---- phase 6: emit via LDS stage + coalesced float4 stores (proven) ------
  if (tid < TOPK) {
    int kp = skeep[tid];
    eout[tid * 6 + 0] = kp ? sx1[tid] : 0.f;
    eout[tid * 6 + 1] = kp ? sy1[tid] : 0.f;
    eout[tid * 6 + 2] = kp ? sx2[tid] : 0.f;
    eout[tid * 6 + 3] = kp ? sy2[tid] : 0.f;
    eout[tid * 6 + 4] = kp ? ssc[tid] : 0.f;
    eout[tid * 6 + 5] = kp ? (float)c : 0.f;
  }
  __syncthreads();

  float4* out4 = (float4*)(out + (size_t)bc * (TOPK * 6));
  const float4* e4 = (const float4*)eout;
  for (int f = tid; f < (TOPK * 6) / 4; f += NTHRB) out4[f] = e4[f];
}

// ---------------------------------------------------------------------------
// Fallback: proven monolithic kernel (strided reads), used only if ws tiny
// ---------------------------------------------------------------------------
__global__ __launch_bounds__(NTHR) void select_nms_k(
    const float* __restrict__ boxes, const float* __restrict__ scores,
    float* __restrict__ out) {
  const int blk = blockIdx.x;
  const int b = blk / NCLS;
  const int c = blk - b * NCLS;
  const int tid = threadIdx.x;

  __shared__ unsigned int hist[256];
  __shared__ unsigned long long keys[1024];
  __shared__ float sx1[TOPK], sy1[TOPK], sx2[TOPK], sy2[TOPK], sar[TOPK], ssc[TOPK];
  __shared__ int skeep[TOPK];
  __shared__ unsigned int sh_cutbits;
  __shared__ int sh_m;

  const float* src = scores + (size_t)b * NANCH * NCLS + c;

  for (int j = tid; j < 256; j += NTHR) hist[j] = 0;
  if (tid == 0) sh_m = 0;
  __syncthreads();

  for (int i = tid; i < NANCH; i += NTHR) hist_add(src[(size_t)i * NCLS], hist);
  __syncthreads();

  if (tid == 0) {
    unsigned int acc = 0;
    int cut = 0;
    for (int bin = 255; bin >= 0; --bin) {
      acc += hist[bin];
      if (acc >= TOPK) { cut = bin; break; }
    }
    sh_cutbits = 0x3F000000u + ((unsigned int)cut << 15);
  }
  __syncthreads();
  const unsigned int cutbits = sh_cutbits;

  for (int i = tid; i < NANCH; i += NTHR) {
    float s = src[(size_t)i * NCLS];
    if (s > 0.5f && __float_as_uint(s) >= cutbits) {
      int slot = atomicAdd(&sh_m, 1);
      if (slot < 1024)
        keys[slot] = ((unsigned long long)__float_as_uint(s) << 32) |
                     (unsigned long long)(0xFFFFFFFFu - (unsigned int)i);
    }
  }
  __syncthreads();
  int M = sh_m; if (M > 1024) M = 1024;
  for (int j = M + tid; j < 1024; j += NTHR) keys[j] = 0ull;

  for (int size = 2; size <= 1024; size <<= 1) {
    for (int st = size >> 1; st > 0; st >>= 1) {
      __syncthreads();
      for (int t = tid; t < 512; t += NTHR) {
        int lo = 2 * t - (t & (st - 1));
        int hi = lo + st;
        bool desc = ((lo & size) == 0);
        unsigned long long a = keys[lo], bb = keys[hi];
        if ((a < bb) == desc) { keys[lo] = bb; keys[hi] = a; }
      }
    }
  }
  __syncthreads();

  if (tid < TOPK) {
    unsigned long long key = keys[tid];
    int valid = (key != 0ull);
    float sc = __uint_as_float((unsigned int)(key >> 32));
    unsigned int idx = 0xFFFFFFFFu - (unsigned int)(key & 0xFFFFFFFFull);
    float4 bx = make_float4(0.f, 0.f, 0.f, 0.f);
    if (valid) bx = ((const float4*)boxes)[(size_t)b * NANCH + idx];
    sx1[tid] = bx.x; sy1[tid] = bx.y; sx2[tid] = bx.z; sy2[tid] = bx.w;
    sar[tid] = __fmul_rn(bx.z - bx.x, bx.w - bx.y);
    ssc[tid] = valid ? sc : 0.f;
    skeep[tid] = valid;
  }
  __syncthreads();

  if (tid < 64) {
    const int lane = tid;
    float x1v[4], y1v[4], x2v[4], y2v[4], av[4];
    int km = 0;
#pragma unroll
    for (int r = 0; r < 4; ++r) {
      int j = lane + (r << 6);
      if (j < TOPK) {
        x1v[r] = sx1[j]; y1v[r] = sy1[j]; x2v[r] = sx2[j]; y2v[r] = sy2[j];
        av[r] = sar[j];
        if (skeep[j]) km |= (1 << r);
      } else {
        x1v[r] = 0.f; y1v[r] = 0.f; x2v[r] = 0.f; y2v[r] = 0.f; av[r] = 0.f;
      }
    }
#pragma unroll
    for (int ri = 0; ri < 4; ++ri) {
      const int imax = (ri == 3) ? (TOPK - 192) : 64;
      for (int li = 0; li < imax; ++li) {
        const int i = (ri << 6) + li;
        int kmi = __shfl(km, li, 64);
        if (!((kmi >> ri) & 1)) continue;
        float xi1 = __shfl(x1v[ri], li, 64);
        float yi1 = __shfl(y1v[ri], li, 64);
        float xi2 = __shfl(x2v[ri], li, 64);
        float yi2 = __shfl(y2v[ri], li, 64);
        float ai  = __shfl(av[ri],  li, 64);
#pragma unroll
        for (int r = 0; r < 4; ++r) {
          int j = lane + (r << 6);
          if (j > i && j < TOPK && ((km >> r) & 1)) {
            float xx1 = fmaxf(xi1, x1v[r]);
            float yy1 = fmaxf(yi1, y1v[r]);
            float xx2 = fminf(xi2, x2v[r]);
            float yy2 = fminf(yi2, y2v[r]);
            float iw = fmaxf(0.f, __fsub_rn(xx2, xx1));
            float ih = fmaxf(0.f, __fsub_rn(yy2, yy1));
            float inter = __fmul_rn(iw, ih);
            float denom = __fsub_rn(__fadd_rn(ai, av[r]), inter);
            float iou = __fdiv_rn(inter, denom);
            if (iou > 0.5f) km &= ~(1 << r);
          }
        }
      }
    }
#pragma unroll
    for (int r = 0; r < 4; ++r) {
      int j = lane + (r << 6);
      if (j < TOPK) skeep[j] = (km >> r) & 1;
    }
  }
  __syncthreads();

  const size_t base = ((size_t)b * NCLS + c) * (TOPK * 6);
  for (int f = tid; f < TOPK * 6; f += NTHR) {
    int k = f / 6, comp = f - k * 6;
    float v = 0.f;
    if (skeep[k]) {
      switch (comp) {
        case 0: v = sx1[k]; break;
        case 1: v = sy1[k]; break;
        case 2: v = sx2[k]; break;
        case 3: v = sy2[k]; break;
        case 4: v = ssc[k]; break;
        default: v = (float)c; break;
      }
    }
    out[base + f] = v;
  }
}

// ---------------------------------------------------------------------------
extern "C" void kernel_launch(void* const* d_in, const int* in_sizes, int n_in,
                              void* d_out, int out_size, void* d_ws, size_t ws_size,
                              hipStream_t stream) {
  (void)in_sizes; (void)n_in; (void)out_size;
  const float* boxes  = (const float*)d_in[0];
  const float* scores = (const float*)d_in[1];
  float* out = (float*)d_out;

  const size_t need_c2 = (size_t)NBC * NCHKP;                          // 174 KB
  const size_t need_cd = (size_t)NBC * NCHK * SLOT * sizeof(uint64_t); // 16.6 MB
  const size_t need = need_c2 + need_cd;

  if (ws_size >= need) {
    char* w = (char*)d_ws;
    unsigned char* cnt2      = (unsigned char*)w;       w += need_c2;
    unsigned long long* cand = (unsigned long long*)w;

    scatter_k<<<dim3(NCHK, B_IMG), NTHR, 0, stream>>>(scores, cnt2, cand);
    backend_k<<<NBC, NTHRB, 0, stream>>>(scores, boxes, cnt2, cand, out);
  } else {
    select_nms_k<<<NBC, NTHR, 0, stream>>>(boxes, scores, out);
  }
}